// Round 1
// baseline (1725.477 us; speedup 1.0000x reference)
//
#include <hip/hip_runtime.h>
#include <math.h>

#define EM_EPS 1e-8f
#define BN_SC 0.999995000037f   // 1/sqrt(1+1e-5)
#define LOG2PI 1.8378770664093453f

// ---------------- conv1 (5x5 s2 VALID) + bn1 ----------------
// x (32,3,32,32), w (256,3,5,5) -> out (32,256,14,14)
__global__ __launch_bounds__(256) void k_conv1(
    const float* __restrict__ x, const float* __restrict__ w,
    const float* __restrict__ g, const float* __restrict__ bb,
    float* __restrict__ out) {
  int idx = blockIdx.x * 256 + threadIdx.x;
  int ox = idx % 14; int t = idx / 14;
  int oy = t % 14; t /= 14;
  int co = t % 256; int b = t / 256;
  const float* xb = x + b * 3 * 1024;
  const float* wc = w + co * 75;
  float acc = 0.f;
  #pragma unroll
  for (int ci = 0; ci < 3; ++ci) {
    const float* xc = xb + ci * 1024 + (oy * 2) * 32 + ox * 2;
    const float* wk = wc + ci * 25;
    #pragma unroll
    for (int kh = 0; kh < 5; ++kh)
      #pragma unroll
      for (int kw = 0; kw < 5; ++kw)
        acc = fmaf(xc[kh * 32 + kw], wk[kh * 5 + kw], acc);
  }
  out[idx] = acc * (g[co] * BN_SC) + bb[co];
}

// ------------- conva+bn+sigmoid and convp+bn fused (3x3 s1 VALID) -------------
// in (32,256,14,14) -> a1 (32,16,12,12), pose1 (32,256,12,12)
__global__ __launch_bounds__(256) void k_conv2(
    const float* __restrict__ in,
    const float* __restrict__ wa, const float* __restrict__ wp,
    const float* __restrict__ ga, const float* __restrict__ bba,
    const float* __restrict__ gp, const float* __restrict__ bbp,
    float* __restrict__ a1, float* __restrict__ pose1) {
  int idx = blockIdx.x * 256 + threadIdx.x;
  int ox = idx % 12; int t = idx / 12;
  int oy = t % 12; t /= 12;
  int c = t % 272; int b = t / 272;
  const float* ib = in + b * 256 * 196 + oy * 14 + ox;
  const float* wptr = (c < 16) ? (wa + c * 2304) : (wp + (c - 16) * 2304);
  float acc = 0.f;
  for (int ci = 0; ci < 256; ++ci) {
    const float* ic = ib + ci * 196;
    const float* wk = wptr + ci * 9;
    acc = fmaf(ic[0],  wk[0], acc);
    acc = fmaf(ic[1],  wk[1], acc);
    acc = fmaf(ic[2],  wk[2], acc);
    acc = fmaf(ic[14], wk[3], acc);
    acc = fmaf(ic[15], wk[4], acc);
    acc = fmaf(ic[16], wk[5], acc);
    acc = fmaf(ic[28], wk[6], acc);
    acc = fmaf(ic[29], wk[7], acc);
    acc = fmaf(ic[30], wk[8], acc);
  }
  if (c < 16) {
    float v = acc * (ga[c] * BN_SC) + bba[c];
    a1[((b * 16 + c) * 12 + oy) * 12 + ox] = 1.f / (1.f + expf(-v));
  } else {
    int co = c - 16;
    pose1[((b * 256 + co) * 12 + oy) * 12 + ox] = acc * (gp[co] * BN_SC) + bbp[co];
  }
}

// ---------------- EM routing (one block per (b, output pixel)) ----------------
// threads: 256 = 16 k_local x 16 pose-elem.  3 EM iterations, one k-pass each.
template<int K, int S, int P, int HIN, int WIN, int OH, int OW, int B>
__global__ __launch_bounds__(256) void k_routing(
    const float* __restrict__ ag,      // (b,16,HIN,WIN)
    const float* __restrict__ poseg,   // (b,256,HIN,WIN)
    const float* __restrict__ Wg,      // (KKA,B,16)
    const float* __restrict__ bu, const float* __restrict__ ba,
    const float* __restrict__ bng, const float* __restrict__ bnb, // optional bn on pose
    float* __restrict__ aout_g,        // (b,B,OH,OW)
    float* __restrict__ pose_out_g) {  // (b,B*16,OH,OW) or null
  constexpr int A = 16;
  constexpr int KK = K * K;
  constexpr int KKA = KK * A;
  constexpr int NCHUNK = KKA / 16;
  constexpr int WSTR = B * 16 + 4;     // pad: k_local shifts banks by 4
  static_assert(KKA % 16 == 0, "KKA");

  __shared__ float s_pp[KKA * 17];
  __shared__ float s_ain[KKA];
  __shared__ float s_W[16 * WSTR];
  __shared__ float s_mu[B * 16];
  __shared__ float s_i2s[B * 16];
  __shared__ float s_part1[4 * B * 16];
  __shared__ float s_part2[4 * B * 16];
  __shared__ float s_partr[4 * B];
  __shared__ float s_loga[B];
  __shared__ float s_L0[B];

  const int t  = threadIdx.x;
  const int kl = t >> 4;
  const int p  = t & 15;
  const int xx = p >> 2;
  const int zz = p & 3;
  const int bi = blockIdx.x;
  const int b  = bi / (OH * OW);
  const int l  = bi % (OH * OW);
  const int oy = l / OW, ox = l % OW;

  // ---- load pose patch (with optional bn) and a patch into LDS ----
  for (int idx = t; idx < KKA * 16; idx += 256) {
    int k = idx >> 4, pe = idx & 15;
    int acap = k & 15, kki = k >> 4;
    int kh = kki / K, kw = kki % K;
    int iy = oy * S - P + kh, ix = ox * S - P + kw;
    float val = 0.f;
    if (iy >= 0 && iy < HIN && ix >= 0 && ix < WIN) {
      int c = acap * 16 + pe;
      val = poseg[((b * 256 + c) * HIN + iy) * WIN + ix];
      if (bng) val = val * (bng[c] * BN_SC) + bnb[c];
    }
    s_pp[k * 17 + pe] = val;
  }
  for (int k = t; k < KKA; k += 256) {
    int acap = k & 15, kki = k >> 4;
    int kh = kki / K, kw = kki % K;
    int iy = oy * S - P + kh, ix = ox * S - P + kw;
    float val = 0.f;
    if (iy >= 0 && iy < HIN && ix >= 0 && ix < WIN)
      val = ag[((b * A + acap) * HIN + iy) * WIN + ix];
    s_ain[k] = val;
  }

  float p95 = 0.95f;
  for (int it = 0; it < 3; ++it) {
    const float lam = 0.01f * (1.0f - p95);
    p95 *= 0.95f;
    float U1[B], U2[B], RS[B];
    #pragma unroll
    for (int j = 0; j < B; ++j) { U1[j] = 0.f; U2[j] = 0.f; RS[j] = 0.f; }

    for (int ch = 0; ch < NCHUNK; ++ch) {
      __syncthreads();                       // guard s_W reuse (and s_pp/s_mu visibility)
      for (int idx = t; idx < 16 * B * 16; idx += 256) {
        int klc = idx / (B * 16);
        int rem = idx - klc * (B * 16);
        s_W[klc * WSTR + rem] = Wg[ch * 16 * B * 16 + idx];
      }
      __syncthreads();

      const int k = ch * 16 + kl;
      const float* pprow = &s_pp[k * 17 + xx * 4];
      const float pp0 = pprow[0], pp1 = pprow[1], pp2 = pprow[2], pp3 = pprow[3];
      const float ain = s_ain[k];
      float vv[B], lnp[B];
      #pragma unroll
      for (int j = 0; j < B; ++j) {
        const float* wr = &s_W[kl * WSTR + j * 16 + zz];
        float v = pp0 * wr[0] + pp1 * wr[4] + pp2 * wr[8] + pp3 * wr[12];
        vv[j] = v;
        if (it > 0) {
          float d = v - s_mu[j * 16 + p];
          float s = d * d * s_i2s[j * 16 + p];
          s += __shfl_xor(s, 1);
          s += __shfl_xor(s, 2);
          s += __shfl_xor(s, 4);
          s += __shfl_xor(s, 8);
          lnp[j] = s_L0[j] + s_loga[j] - s;   // ln_p + log(a_out+eps)
        }
      }
      float r[B];
      if (it == 0) {
        #pragma unroll
        for (int j = 0; j < B; ++j) r[j] = 1.0f / (float)B;
      } else {
        float m = lnp[0];
        #pragma unroll
        for (int j = 1; j < B; ++j) m = fmaxf(m, lnp[j]);
        float sum = 0.f;
        #pragma unroll
        for (int j = 0; j < B; ++j) { r[j] = expf(lnp[j] - m); sum += r[j]; }
        float inv = 1.f / sum;
        #pragma unroll
        for (int j = 0; j < B; ++j) r[j] *= inv;
      }
      #pragma unroll
      for (int j = 0; j < B; ++j) {
        float ra = r[j] * ain;
        RS[j] += ra;
        U1[j] += ra * vv[j];
        U2[j] += ra * vv[j] * vv[j];
      }
    }

    // reduce over k_local: within-wave (4 k_locals) via shfl, cross-wave via LDS
    #pragma unroll
    for (int j = 0; j < B; ++j) {
      U1[j] += __shfl_xor(U1[j], 16); U1[j] += __shfl_xor(U1[j], 32);
      U2[j] += __shfl_xor(U2[j], 16); U2[j] += __shfl_xor(U2[j], 32);
      RS[j] += __shfl_xor(RS[j], 16); RS[j] += __shfl_xor(RS[j], 32);
    }
    __syncthreads();
    const int wv = t >> 6;
    if ((t & 63) < 16) {
      #pragma unroll
      for (int j = 0; j < B; ++j) {
        s_part1[(wv * B + j) * 16 + p] = U1[j];
        s_part2[(wv * B + j) * 16 + p] = U2[j];
      }
      if (p == 0) {
        #pragma unroll
        for (int j = 0; j < B; ++j) s_partr[wv * B + j] = RS[j];
      }
    }
    __syncthreads();

    if (t < B * 16) {
      const int j = t >> 4;
      float u1 = 0.f, u2 = 0.f;
      #pragma unroll
      for (int w2 = 0; w2 < 4; ++w2) {
        u1 += s_part1[(w2 * B + j) * 16 + p];
        u2 += s_part2[(w2 * B + j) * 16 + p];
      }
      float rs = s_partr[j] + s_partr[B + j] + s_partr[2 * B + j] + s_partr[3 * B + j];
      float inv = 1.f / (rs + EM_EPS);
      float mu  = u1 * inv;
      float Cc  = rs * inv;
      float sig = u2 * inv - mu * mu * (2.f - Cc) + EM_EPS;
      float ls  = logf(sig);
      float ca  = bu[j] + 0.5f * ls;
      float lsum = ls;
      ca += __shfl_xor(ca, 1); lsum += __shfl_xor(lsum, 1);
      ca += __shfl_xor(ca, 2); lsum += __shfl_xor(lsum, 2);
      ca += __shfl_xor(ca, 4); lsum += __shfl_xor(lsum, 4);
      ca += __shfl_xor(ca, 8); lsum += __shfl_xor(lsum, 8);
      float cost = ca * rs;
      float aout = 1.f / (1.f + expf(-(lam * (ba[j] - cost))));
      if (it < 2) {
        s_mu[t]  = mu;
        s_i2s[t] = 0.5f / sig;
        if (p == 0) {
          s_loga[j] = logf(aout + EM_EPS);
          s_L0[j]   = -0.5f * (16.f * LOG2PI + lsum);
        }
      } else {
        if (p == 0) aout_g[((b * B + j) * OH + oy) * OW + ox] = aout;
        if (pose_out_g)
          pose_out_g[((b * (B * 16) + j * 16 + p) * OH + oy) * OW + ox] = mu;
      }
    }
    // next pass's first __syncthreads() guards s_mu/s_loga consumption
  }
}

// ---------------- spatial mean ----------------
__global__ __launch_bounds__(64) void k_mean(const float* __restrict__ a4,
                                             float* __restrict__ out) {
  int idx = blockIdx.x * 64 + threadIdx.x;
  if (idx >= 320) return;
  const float* pa = a4 + idx * 25;
  float s = 0.f;
  #pragma unroll
  for (int i = 0; i < 25; ++i) s += pa[i];
  out[idx] = s * (1.f / 25.f);
}

extern "C" void kernel_launch(void* const* d_in, const int* in_sizes, int n_in,
                              void* d_out, int out_size, void* d_ws, size_t ws_size,
                              hipStream_t stream) {
  const float* x       = (const float*)d_in[0];
  const float* conv1_w = (const float*)d_in[1];
  const float* bn1_g   = (const float*)d_in[2];
  const float* bn1_b   = (const float*)d_in[3];
  const float* conva_w = (const float*)d_in[4];
  const float* bna_g   = (const float*)d_in[5];
  const float* bna_b   = (const float*)d_in[6];
  const float* convp_w = (const float*)d_in[7];
  const float* bnp_g   = (const float*)d_in[8];
  const float* bnp_b   = (const float*)d_in[9];
  const float* W1      = (const float*)d_in[10];
  const float* bu1     = (const float*)d_in[11];
  const float* ba1     = (const float*)d_in[12];
  const float* bnc1_g  = (const float*)d_in[13];
  const float* bnc1_b  = (const float*)d_in[14];
  const float* W2      = (const float*)d_in[15];
  const float* bu2     = (const float*)d_in[16];
  const float* ba2     = (const float*)d_in[17];
  const float* bnc2_g  = (const float*)d_in[18];
  const float* bnc2_b  = (const float*)d_in[19];
  const float* Wfc     = (const float*)d_in[20];
  const float* bufc    = (const float*)d_in[21];
  const float* bafc    = (const float*)d_in[22];

  float* ws    = (float*)d_ws;
  float* out1  = ws;                          // 32*256*14*14 = 1605632
  float* a1    = out1  + 32 * 256 * 14 * 14;  // 73728
  float* pose1 = a1    + 32 * 16 * 12 * 12;   // 1179648
  float* a2    = pose1 + 32 * 256 * 12 * 12;  // 18432
  float* pose2 = a2    + 32 * 16 * 6 * 6;     // 294912
  float* a3    = pose2 + 32 * 256 * 6 * 6;    // 18432
  float* pose3 = a3    + 32 * 16 * 6 * 6;     // 294912
  float* a4    = pose3 + 32 * 256 * 6 * 6;    // 8000

  k_conv1<<<6272, 256, 0, stream>>>(x, conv1_w, bn1_g, bn1_b, out1);
  k_conv2<<<4896, 256, 0, stream>>>(out1, conva_w, convp_w, bna_g, bna_b,
                                    bnp_g, bnp_b, a1, pose1);
  k_routing<3, 2, 1, 12, 12, 6, 6, 16><<<32 * 36, 256, 0, stream>>>(
      a1, pose1, W1, bu1, ba1, nullptr, nullptr, a2, pose2);
  k_routing<3, 1, 1, 6, 6, 6, 6, 16><<<32 * 36, 256, 0, stream>>>(
      a2, pose2, W2, bu2, ba2, bnc1_g, bnc1_b, a3, pose3);
  k_routing<4, 1, 1, 6, 6, 5, 5, 10><<<32 * 25, 256, 0, stream>>>(
      a3, pose3, Wfc, bufc, bafc, bnc2_g, bnc2_b, a4, nullptr);
  k_mean<<<5, 64, 0, stream>>>(a4, (float*)d_out);
}

// Round 2
// 1255.527 us; speedup vs baseline: 1.3743x; 1.3743x over previous
//
#include <hip/hip_runtime.h>
#include <math.h>

#define EM_EPS 1e-8f
#define BN_SC 0.999995000037f   // 1/sqrt(1+1e-5)
#define LOG2PI 1.8378770664093453f

// ---------------- conv1 (5x5 s2 VALID) + bn1 ----------------
// x (32,3,32,32), w (256,3,5,5) -> out (32,256,14,14)
__global__ __launch_bounds__(256) void k_conv1(
    const float* __restrict__ x, const float* __restrict__ w,
    const float* __restrict__ g, const float* __restrict__ bb,
    float* __restrict__ out) {
  int idx = blockIdx.x * 256 + threadIdx.x;
  int ox = idx % 14; int t = idx / 14;
  int oy = t % 14; t /= 14;
  int co = t % 256; int b = t / 256;
  const float* xb = x + b * 3 * 1024;
  const float* wc = w + co * 75;
  float acc = 0.f;
  #pragma unroll
  for (int ci = 0; ci < 3; ++ci) {
    const float* xc = xb + ci * 1024 + (oy * 2) * 32 + ox * 2;
    const float* wk = wc + ci * 25;
    #pragma unroll
    for (int kh = 0; kh < 5; ++kh)
      #pragma unroll
      for (int kw = 0; kw < 5; ++kw)
        acc = fmaf(xc[kh * 32 + kw], wk[kh * 5 + kw], acc);
  }
  out[idx] = acc * (g[co] * BN_SC) + bb[co];
}

// ------------- conva+bn+sigmoid and convp+bn fused (3x3 s1 VALID) -------------
// LDS-staged register-blocked implicit GEMM.
// grid = 32 batches x 9 co-groups (32 ch each, logical co 0..287, >=272 masked)
// 192 threads = 12 pixel-rows x 16 co-pairs; thread computes 2 co x 12 px.
__global__ __launch_bounds__(192) void k_conv2(
    const float* __restrict__ in,
    const float* __restrict__ wa, const float* __restrict__ wp,
    const float* __restrict__ ga, const float* __restrict__ bba,
    const float* __restrict__ gp, const float* __restrict__ bbp,
    float* __restrict__ a1, float* __restrict__ pose1) {
  __shared__ float s_in[16 * 14 * 16];   // [ci][iy 0..13][ix pad16]  14.3 KB
  __shared__ float s_w[16 * 9 * 34];     // [ci][tap][co pad34]       19.6 KB

  const int t   = threadIdx.x;
  const int row = t >> 4;     // 0..11  output pixel row
  const int cg  = t & 15;     // co-pair index
  const int b   = blockIdx.x / 9;
  const int gco = (blockIdx.x % 9) * 32;
  const float* inb = in + b * 50176;

  float acc[2][12];
  #pragma unroll
  for (int u = 0; u < 2; ++u)
    #pragma unroll
    for (int px = 0; px < 12; ++px) acc[u][px] = 0.f;

  for (int ch = 0; ch < 16; ++ch) {
    __syncthreads();
    // stage input chunk (16 in-channels, contiguous 3136 floats in global)
    for (int idx = t; idx < 3136; idx += 192) {
      int ci = idx / 196, r = idx - ci * 196;
      int iy = r / 14, ix = r - iy * 14;
      s_in[ci * 224 + iy * 16 + ix] = inb[ch * 3136 + idx];
    }
    // stage weight chunk transposed: [ci][tap][co]
    for (int idx = t; idx < 4608; idx += 192) {
      int co = idx / 144, rem = idx - co * 144;
      int c = gco + co;
      float val = 0.f;
      if (c < 272) {
        const float* wrow = (c < 16) ? (wa + c * 2304) : (wp + (c - 16) * 2304);
        val = wrow[ch * 144 + rem];
      }
      s_w[rem * 34 + co] = val;
    }
    __syncthreads();

    for (int ci = 0; ci < 16; ++ci) {
      float rin[3][16];
      #pragma unroll
      for (int kh = 0; kh < 3; ++kh) {
        const float4* rp = (const float4*)&s_in[ci * 224 + (row + kh) * 16];
        #pragma unroll
        for (int x = 0; x < 4; ++x)
          *(float4*)&rin[kh][x * 4] = rp[x];
      }
      #pragma unroll
      for (int kh = 0; kh < 3; ++kh) {
        #pragma unroll
        for (int kw = 0; kw < 3; ++kw) {
          float2 wv = *(const float2*)&s_w[(ci * 9 + kh * 3 + kw) * 34 + cg * 2];
          #pragma unroll
          for (int px = 0; px < 12; ++px) {
            float iv = rin[kh][px + kw];
            acc[0][px] = fmaf(iv, wv.x, acc[0][px]);
            acc[1][px] = fmaf(iv, wv.y, acc[1][px]);
          }
        }
      }
    }
  }

  #pragma unroll
  for (int u = 0; u < 2; ++u) {
    int c = gco + cg * 2 + u;
    if (c >= 272) continue;
    if (c < 16) {
      float g_ = ga[c] * BN_SC, b_ = bba[c];
      float* dst = a1 + ((b * 16 + c) * 12 + row) * 12;
      #pragma unroll
      for (int px = 0; px < 12; ++px) {
        float v = acc[u][px] * g_ + b_;
        dst[px] = 1.f / (1.f + expf(-v));
      }
    } else {
      int cp = c - 16;
      float g_ = gp[cp] * BN_SC, b_ = bbp[cp];
      float* dst = pose1 + ((b * 256 + cp) * 12 + row) * 12;
      #pragma unroll
      for (int px = 0; px < 12; ++px)
        dst[px] = acc[u][px] * g_ + b_;
    }
  }
}

// ---------------- EM routing (one block per (b, output pixel)) ----------------
// threads: 256 = 16 k_local x 16 pose-elem.  3 EM iterations, one k-pass each.
template<int K, int S, int P, int HIN, int WIN, int OH, int OW, int B>
__global__ __launch_bounds__(256) void k_routing(
    const float* __restrict__ ag,      // (b,16,HIN,WIN)
    const float* __restrict__ poseg,   // (b,256,HIN,WIN)
    const float* __restrict__ Wg,      // (KKA,B,16)
    const float* __restrict__ bu, const float* __restrict__ ba,
    const float* __restrict__ bng, const float* __restrict__ bnb, // optional bn on pose
    float* __restrict__ aout_g,        // (b,B,OH,OW)
    float* __restrict__ pose_out_g) {  // (b,B*16,OH,OW) or null
  constexpr int A = 16;
  constexpr int KK = K * K;
  constexpr int KKA = KK * A;
  constexpr int NCHUNK = KKA / 16;
  constexpr int WSTR = B * 16 + 4;     // pad: k_local shifts banks by 4
  static_assert(KKA % 16 == 0, "KKA");

  __shared__ float s_pp[KKA * 17];
  __shared__ float s_ain[KKA];
  __shared__ float s_W[16 * WSTR];
  __shared__ float s_mu[B * 16];
  __shared__ float s_i2s[B * 16];
  __shared__ float s_part1[4 * B * 16];
  __shared__ float s_part2[4 * B * 16];
  __shared__ float s_partr[4 * B];
  __shared__ float s_loga[B];
  __shared__ float s_L0[B];

  const int t  = threadIdx.x;
  const int kl = t >> 4;
  const int p  = t & 15;
  const int xx = p >> 2;
  const int zz = p & 3;
  const int bi = blockIdx.x;
  const int b  = bi / (OH * OW);
  const int l  = bi % (OH * OW);
  const int oy = l / OW, ox = l % OW;

  // ---- load pose patch (with optional bn) and a patch into LDS ----
  for (int idx = t; idx < KKA * 16; idx += 256) {
    int k = idx >> 4, pe = idx & 15;
    int acap = k & 15, kki = k >> 4;
    int kh = kki / K, kw = kki % K;
    int iy = oy * S - P + kh, ix = ox * S - P + kw;
    float val = 0.f;
    if (iy >= 0 && iy < HIN && ix >= 0 && ix < WIN) {
      int c = acap * 16 + pe;
      val = poseg[((b * 256 + c) * HIN + iy) * WIN + ix];
      if (bng) val = val * (bng[c] * BN_SC) + bnb[c];
    }
    s_pp[k * 17 + pe] = val;
  }
  for (int k = t; k < KKA; k += 256) {
    int acap = k & 15, kki = k >> 4;
    int kh = kki / K, kw = kki % K;
    int iy = oy * S - P + kh, ix = ox * S - P + kw;
    float val = 0.f;
    if (iy >= 0 && iy < HIN && ix >= 0 && ix < WIN)
      val = ag[((b * A + acap) * HIN + iy) * WIN + ix];
    s_ain[k] = val;
  }

  float p95 = 0.95f;
  for (int it = 0; it < 3; ++it) {
    const float lam = 0.01f * (1.0f - p95);
    p95 *= 0.95f;
    float U1[B], U2[B], RS[B];
    #pragma unroll
    for (int j = 0; j < B; ++j) { U1[j] = 0.f; U2[j] = 0.f; RS[j] = 0.f; }

    for (int ch = 0; ch < NCHUNK; ++ch) {
      __syncthreads();                       // guard s_W reuse (and s_pp/s_mu visibility)
      for (int idx = t; idx < 16 * B * 16; idx += 256) {
        int klc = idx / (B * 16);
        int rem = idx - klc * (B * 16);
        s_W[klc * WSTR + rem] = Wg[ch * 16 * B * 16 + idx];
      }
      __syncthreads();

      const int k = ch * 16 + kl;
      const float* pprow = &s_pp[k * 17 + xx * 4];
      const float pp0 = pprow[0], pp1 = pprow[1], pp2 = pprow[2], pp3 = pprow[3];
      const float ain = s_ain[k];
      float vv[B], lnp[B];
      #pragma unroll
      for (int j = 0; j < B; ++j) {
        const float* wr = &s_W[kl * WSTR + j * 16 + zz];
        float v = pp0 * wr[0] + pp1 * wr[4] + pp2 * wr[8] + pp3 * wr[12];
        vv[j] = v;
        if (it > 0) {
          float d = v - s_mu[j * 16 + p];
          float s = d * d * s_i2s[j * 16 + p];
          s += __shfl_xor(s, 1);
          s += __shfl_xor(s, 2);
          s += __shfl_xor(s, 4);
          s += __shfl_xor(s, 8);
          lnp[j] = s_L0[j] + s_loga[j] - s;   // ln_p + log(a_out+eps)
        }
      }
      float r[B];
      if (it == 0) {
        #pragma unroll
        for (int j = 0; j < B; ++j) r[j] = 1.0f / (float)B;
      } else {
        float m = lnp[0];
        #pragma unroll
        for (int j = 1; j < B; ++j) m = fmaxf(m, lnp[j]);
        float sum = 0.f;
        #pragma unroll
        for (int j = 0; j < B; ++j) { r[j] = expf(lnp[j] - m); sum += r[j]; }
        float inv = 1.f / sum;
        #pragma unroll
        for (int j = 0; j < B; ++j) r[j] *= inv;
      }
      #pragma unroll
      for (int j = 0; j < B; ++j) {
        float ra = r[j] * ain;
        RS[j] += ra;
        U1[j] += ra * vv[j];
        U2[j] += ra * vv[j] * vv[j];
      }
    }

    // reduce over k_local: within-wave (4 k_locals) via shfl, cross-wave via LDS
    #pragma unroll
    for (int j = 0; j < B; ++j) {
      U1[j] += __shfl_xor(U1[j], 16); U1[j] += __shfl_xor(U1[j], 32);
      U2[j] += __shfl_xor(U2[j], 16); U2[j] += __shfl_xor(U2[j], 32);
      RS[j] += __shfl_xor(RS[j], 16); RS[j] += __shfl_xor(RS[j], 32);
    }
    __syncthreads();
    const int wv = t >> 6;
    if ((t & 63) < 16) {
      #pragma unroll
      for (int j = 0; j < B; ++j) {
        s_part1[(wv * B + j) * 16 + p] = U1[j];
        s_part2[(wv * B + j) * 16 + p] = U2[j];
      }
      if (p == 0) {
        #pragma unroll
        for (int j = 0; j < B; ++j) s_partr[wv * B + j] = RS[j];
      }
    }
    __syncthreads();

    if (t < B * 16) {
      const int j = t >> 4;
      float u1 = 0.f, u2 = 0.f;
      #pragma unroll
      for (int w2 = 0; w2 < 4; ++w2) {
        u1 += s_part1[(w2 * B + j) * 16 + p];
        u2 += s_part2[(w2 * B + j) * 16 + p];
      }
      float rs = s_partr[j] + s_partr[B + j] + s_partr[2 * B + j] + s_partr[3 * B + j];
      float inv = 1.f / (rs + EM_EPS);
      float mu  = u1 * inv;
      float Cc  = rs * inv;
      float sig = u2 * inv - mu * mu * (2.f - Cc) + EM_EPS;
      float ls  = logf(sig);
      float ca  = bu[j] + 0.5f * ls;
      float lsum = ls;
      ca += __shfl_xor(ca, 1); lsum += __shfl_xor(lsum, 1);
      ca += __shfl_xor(ca, 2); lsum += __shfl_xor(lsum, 2);
      ca += __shfl_xor(ca, 4); lsum += __shfl_xor(lsum, 4);
      ca += __shfl_xor(ca, 8); lsum += __shfl_xor(lsum, 8);
      float cost = ca * rs;
      float aout = 1.f / (1.f + expf(-(lam * (ba[j] - cost))));
      if (it < 2) {
        s_mu[t]  = mu;
        s_i2s[t] = 0.5f / sig;
        if (p == 0) {
          s_loga[j] = logf(aout + EM_EPS);
          s_L0[j]   = -0.5f * (16.f * LOG2PI + lsum);
        }
      } else {
        if (p == 0) aout_g[((b * B + j) * OH + oy) * OW + ox] = aout;
        if (pose_out_g)
          pose_out_g[((b * (B * 16) + j * 16 + p) * OH + oy) * OW + ox] = mu;
      }
    }
    // next pass's first __syncthreads() guards s_mu/s_loga consumption
  }
}

// ---------------- spatial mean ----------------
__global__ __launch_bounds__(64) void k_mean(const float* __restrict__ a4,
                                             float* __restrict__ out) {
  int idx = blockIdx.x * 64 + threadIdx.x;
  if (idx >= 320) return;
  const float* pa = a4 + idx * 25;
  float s = 0.f;
  #pragma unroll
  for (int i = 0; i < 25; ++i) s += pa[i];
  out[idx] = s * (1.f / 25.f);
}

extern "C" void kernel_launch(void* const* d_in, const int* in_sizes, int n_in,
                              void* d_out, int out_size, void* d_ws, size_t ws_size,
                              hipStream_t stream) {
  const float* x       = (const float*)d_in[0];
  const float* conv1_w = (const float*)d_in[1];
  const float* bn1_g   = (const float*)d_in[2];
  const float* bn1_b   = (const float*)d_in[3];
  const float* conva_w = (const float*)d_in[4];
  const float* bna_g   = (const float*)d_in[5];
  const float* bna_b   = (const float*)d_in[6];
  const float* convp_w = (const float*)d_in[7];
  const float* bnp_g   = (const float*)d_in[8];
  const float* bnp_b   = (const float*)d_in[9];
  const float* W1      = (const float*)d_in[10];
  const float* bu1     = (const float*)d_in[11];
  const float* ba1     = (const float*)d_in[12];
  const float* bnc1_g  = (const float*)d_in[13];
  const float* bnc1_b  = (const float*)d_in[14];
  const float* W2      = (const float*)d_in[15];
  const float* bu2     = (const float*)d_in[16];
  const float* ba2     = (const float*)d_in[17];
  const float* bnc2_g  = (const float*)d_in[18];
  const float* bnc2_b  = (const float*)d_in[19];
  const float* Wfc     = (const float*)d_in[20];
  const float* bufc    = (const float*)d_in[21];
  const float* bafc    = (const float*)d_in[22];

  float* ws    = (float*)d_ws;
  float* out1  = ws;                          // 32*256*14*14 = 1605632
  float* a1    = out1  + 32 * 256 * 14 * 14;  // 73728
  float* pose1 = a1    + 32 * 16 * 12 * 12;   // 1179648
  float* a2    = pose1 + 32 * 256 * 12 * 12;  // 18432
  float* pose2 = a2    + 32 * 16 * 6 * 6;     // 294912
  float* a3    = pose2 + 32 * 256 * 6 * 6;    // 18432
  float* pose3 = a3    + 32 * 16 * 6 * 6;     // 294912
  float* a4    = pose3 + 32 * 256 * 6 * 6;    // 8000

  k_conv1<<<6272, 256, 0, stream>>>(x, conv1_w, bn1_g, bn1_b, out1);
  k_conv2<<<288, 192, 0, stream>>>(out1, conva_w, convp_w, bna_g, bna_b,
                                   bnp_g, bnp_b, a1, pose1);
  k_routing<3, 2, 1, 12, 12, 6, 6, 16><<<32 * 36, 256, 0, stream>>>(
      a1, pose1, W1, bu1, ba1, nullptr, nullptr, a2, pose2);
  k_routing<3, 1, 1, 6, 6, 6, 6, 16><<<32 * 36, 256, 0, stream>>>(
      a2, pose2, W2, bu2, ba2, bnc1_g, bnc1_b, a3, pose3);
  k_routing<4, 1, 1, 6, 6, 5, 5, 10><<<32 * 25, 256, 0, stream>>>(
      a3, pose3, Wfc, bufc, bafc, bnc2_g, bnc2_b, a4, nullptr);
  k_mean<<<5, 64, 0, stream>>>(a4, (float*)d_out);
}

// Round 3
// 741.894 us; speedup vs baseline: 2.3258x; 1.6923x over previous
//
#include <hip/hip_runtime.h>
#include <math.h>

#define EM_EPS 1e-8f
#define BN_SC 0.999995000037f   // 1/sqrt(1+1e-5)
#define LOG2PI 1.8378770664093453f

// ---------------- conv1 (5x5 s2 VALID) + bn1 ----------------
// x (32,3,32,32), w (256,3,5,5) -> out (32,256,14,14)
__global__ __launch_bounds__(256) void k_conv1(
    const float* __restrict__ x, const float* __restrict__ w,
    const float* __restrict__ g, const float* __restrict__ bb,
    float* __restrict__ out) {
  int idx = blockIdx.x * 256 + threadIdx.x;
  int ox = idx % 14; int t = idx / 14;
  int oy = t % 14; t /= 14;
  int co = t % 256; int b = t / 256;
  const float* xb = x + b * 3 * 1024;
  const float* wc = w + co * 75;
  float acc = 0.f;
  #pragma unroll
  for (int ci = 0; ci < 3; ++ci) {
    const float* xc = xb + ci * 1024 + (oy * 2) * 32 + ox * 2;
    const float* wk = wc + ci * 25;
    #pragma unroll
    for (int kh = 0; kh < 5; ++kh)
      #pragma unroll
      for (int kw = 0; kw < 5; ++kw)
        acc = fmaf(xc[kh * 32 + kw], wk[kh * 5 + kw], acc);
  }
  out[idx] = acc * (g[co] * BN_SC) + bb[co];
}

// ------------- conva+bn+sigmoid and convp+bn fused (3x3 s1 VALID) -------------
// LDS-staged register-blocked implicit GEMM.
__global__ __launch_bounds__(192) void k_conv2(
    const float* __restrict__ in,
    const float* __restrict__ wa, const float* __restrict__ wp,
    const float* __restrict__ ga, const float* __restrict__ bba,
    const float* __restrict__ gp, const float* __restrict__ bbp,
    float* __restrict__ a1, float* __restrict__ pose1) {
  __shared__ float s_in[16 * 14 * 16];   // [ci][iy 0..13][ix pad16]
  __shared__ float s_w[16 * 9 * 34];     // [ci][tap][co pad34]

  const int t   = threadIdx.x;
  const int row = t >> 4;     // 0..11  output pixel row
  const int cg  = t & 15;     // co-pair index
  const int b   = blockIdx.x / 9;
  const int gco = (blockIdx.x % 9) * 32;
  const float* inb = in + b * 50176;

  float acc[2][12];
  #pragma unroll
  for (int u = 0; u < 2; ++u)
    #pragma unroll
    for (int px = 0; px < 12; ++px) acc[u][px] = 0.f;

  for (int ch = 0; ch < 16; ++ch) {
    __syncthreads();
    for (int idx = t; idx < 3136; idx += 192) {
      int ci = idx / 196, r = idx - ci * 196;
      int iy = r / 14, ix = r - iy * 14;
      s_in[ci * 224 + iy * 16 + ix] = inb[ch * 3136 + idx];
    }
    for (int idx = t; idx < 4608; idx += 192) {
      int co = idx / 144, rem = idx - co * 144;
      int c = gco + co;
      float val = 0.f;
      if (c < 272) {
        const float* wrow = (c < 16) ? (wa + c * 2304) : (wp + (c - 16) * 2304);
        val = wrow[ch * 144 + rem];
      }
      s_w[rem * 34 + co] = val;
    }
    __syncthreads();

    for (int ci = 0; ci < 16; ++ci) {
      float rin[3][16];
      #pragma unroll
      for (int kh = 0; kh < 3; ++kh) {
        const float4* rp = (const float4*)&s_in[ci * 224 + (row + kh) * 16];
        #pragma unroll
        for (int x = 0; x < 4; ++x)
          *(float4*)&rin[kh][x * 4] = rp[x];
      }
      #pragma unroll
      for (int kh = 0; kh < 3; ++kh) {
        #pragma unroll
        for (int kw = 0; kw < 3; ++kw) {
          float2 wv = *(const float2*)&s_w[(ci * 9 + kh * 3 + kw) * 34 + cg * 2];
          #pragma unroll
          for (int px = 0; px < 12; ++px) {
            float iv = rin[kh][px + kw];
            acc[0][px] = fmaf(iv, wv.x, acc[0][px]);
            acc[1][px] = fmaf(iv, wv.y, acc[1][px]);
          }
        }
      }
    }
  }

  #pragma unroll
  for (int u = 0; u < 2; ++u) {
    int c = gco + cg * 2 + u;
    if (c >= 272) continue;
    if (c < 16) {
      float g_ = ga[c] * BN_SC, b_ = bba[c];
      float* dst = a1 + ((b * 16 + c) * 12 + row) * 12;
      #pragma unroll
      for (int px = 0; px < 12; ++px) {
        float v = acc[u][px] * g_ + b_;
        dst[px] = 1.f / (1.f + expf(-v));
      }
    } else {
      int cp = c - 16;
      float g_ = gp[cp] * BN_SC, b_ = bbp[cp];
      float* dst = pose1 + ((b * 256 + cp) * 12 + row) * 12;
      #pragma unroll
      for (int px = 0; px < 12; ++px)
        dst[px] = acc[u][px] * g_ + b_;
    }
  }
}

// ---------------- EM routing: block = one (b, output pixel) ----------------
// 256 threads = 4 waves; wave w owns k in [w*KKA/4, (w+1)*KKA/4).
// lane = x*16 + j : x = pose row (p-group), j = output capsule.
// W read straight from global (L1/L2-resident); mu/sigma/L0/loga live in regs.
template<int K, int S, int P, int HIN, int WIN, int OH, int OW, int B>
__global__ __launch_bounds__(256) void k_routing(
    const float* __restrict__ ag,      // (b,16,HIN,WIN)
    const float* __restrict__ poseg,   // (b,256,HIN,WIN)
    const float* __restrict__ Wg,      // (KKA,B,4,4)
    const float* __restrict__ bu, const float* __restrict__ ba,
    const float* __restrict__ bng, const float* __restrict__ bnb,
    float* __restrict__ aout_g,        // (b,B,OH,OW)
    float* __restrict__ pose_out_g) {  // (b,B*16,OH,OW) or null
  constexpr int A = 16;
  constexpr int KK = K * K;
  constexpr int KKA = KK * A;
  constexpr int KPW = KKA / 4;
  static_assert(KKA % 4 == 0, "KKA%4");

  __shared__ __attribute__((aligned(16))) float s_pp[KKA * 16];
  __shared__ float s_ain[KKA];
  __shared__ float s_part[4][9][64];

  const int t  = threadIdx.x;
  const int wv = t >> 6;
  const int ln = t & 63;
  const int x  = ln >> 4;
  const int j  = ln & 15;
  const int jc = (j < B) ? j : 0;
  const bool jvalid = (j < B);

  const int bi = blockIdx.x;
  const int b  = bi / (OH * OW);
  const int l  = bi % (OH * OW);
  const int oy = l / OW, ox = l % OW;

  // ---- stage pose patch (+bn) and a patch into LDS ----
  for (int idx = t; idx < KKA * 16; idx += 256) {
    int k = idx >> 4, pe = idx & 15;
    int acap = k & 15, kki = k >> 4;
    int kh = kki / K, kw = kki % K;
    int iy = oy * S - P + kh, ix = ox * S - P + kw;
    float val = 0.f;
    if (iy >= 0 && iy < HIN && ix >= 0 && ix < WIN) {
      int c = acap * 16 + pe;
      val = poseg[((b * 256 + c) * HIN + iy) * WIN + ix];
      if (bng) val = val * (bng[c] * BN_SC) + bnb[c];
    }
    s_pp[idx] = val;
  }
  for (int k = t; k < KKA; k += 256) {
    int acap = k & 15, kki = k >> 4;
    int kh = kki / K, kw = kki % K;
    int iy = oy * S - P + kh, ix = ox * S - P + kw;
    float val = 0.f;
    if (iy >= 0 && iy < HIN && ix >= 0 && ix < WIN)
      val = ag[((b * A + acap) * HIN + iy) * WIN + ix];
    s_ain[k] = val;
  }
  __syncthreads();

  const float bu_j = bu[jc];
  const float ba_j = ba[jc];
  const int k0 = wv * KPW;

  float mu[4] = {0, 0, 0, 0}, i2s[4] = {0, 0, 0, 0};
  float L0 = 0.f, loga = 0.f;

  float p95 = 0.95f;
  for (int it = 0; it < 3; ++it) {
    const float lam = 0.01f * (1.0f - p95);
    p95 *= 0.95f;
    float U1[4] = {0, 0, 0, 0}, U2[4] = {0, 0, 0, 0}, RS = 0.f;

    for (int kk2 = 0; kk2 < KPW; ++kk2) {
      const int k = k0 + kk2;
      const float4 pp4 = *(const float4*)&s_pp[k * 16 + x * 4];
      const float* wr = Wg + (size_t)(k * B + jc) * 16;
      const float4 w0 = *(const float4*)(wr);
      const float4 w1 = *(const float4*)(wr + 4);
      const float4 w2 = *(const float4*)(wr + 8);
      const float4 w3 = *(const float4*)(wr + 12);
      float v0 = pp4.x * w0.x + pp4.y * w1.x + pp4.z * w2.x + pp4.w * w3.x;
      float v1 = pp4.x * w0.y + pp4.y * w1.y + pp4.z * w2.y + pp4.w * w3.y;
      float v2 = pp4.x * w0.z + pp4.y * w1.z + pp4.z * w2.z + pp4.w * w3.z;
      float v3 = pp4.x * w0.w + pp4.y * w1.w + pp4.z * w2.w + pp4.w * w3.w;
      const float ain = s_ain[k];
      float r;
      if (it == 0) {
        r = 1.0f / (float)B;
      } else {
        float d0 = v0 - mu[0], d1 = v1 - mu[1];
        float d2 = v2 - mu[2], d3 = v3 - mu[3];
        float s = d0 * d0 * i2s[0] + d1 * d1 * i2s[1]
                + d2 * d2 * i2s[2] + d3 * d3 * i2s[3];
        s += __shfl_xor(s, 16); s += __shfl_xor(s, 32);   // sum over p
        float lnp = L0 + loga - s;
        if (!jvalid) lnp = -1e30f;
        float mx = lnp;
        mx = fmaxf(mx, __shfl_xor(mx, 1));
        mx = fmaxf(mx, __shfl_xor(mx, 2));
        mx = fmaxf(mx, __shfl_xor(mx, 4));
        mx = fmaxf(mx, __shfl_xor(mx, 8));
        float e = __expf(lnp - mx);
        float sm = e;
        sm += __shfl_xor(sm, 1); sm += __shfl_xor(sm, 2);
        sm += __shfl_xor(sm, 4); sm += __shfl_xor(sm, 8);
        r = e * __builtin_amdgcn_rcpf(sm);
      }
      float ra = r * ain;
      RS += ra;
      float t0 = ra * v0, t1 = ra * v1, t2 = ra * v2, t3 = ra * v3;
      U1[0] += t0; U1[1] += t1; U1[2] += t2; U1[3] += t3;
      U2[0] += t0 * v0; U2[1] += t1 * v1; U2[2] += t2 * v2; U2[3] += t3 * v3;
    }

    // ---- cross-wave reduction (sum over the 4 k-partitions) ----
    s_part[wv][0][ln] = U1[0]; s_part[wv][1][ln] = U1[1];
    s_part[wv][2][ln] = U1[2]; s_part[wv][3][ln] = U1[3];
    s_part[wv][4][ln] = U2[0]; s_part[wv][5][ln] = U2[1];
    s_part[wv][6][ln] = U2[2]; s_part[wv][7][ln] = U2[3];
    s_part[wv][8][ln] = RS;
    __syncthreads();
    float fU1[4] = {0, 0, 0, 0}, fU2[4] = {0, 0, 0, 0}, fRS = 0.f;
    #pragma unroll
    for (int w2 = 0; w2 < 4; ++w2) {
      fU1[0] += s_part[w2][0][ln]; fU1[1] += s_part[w2][1][ln];
      fU1[2] += s_part[w2][2][ln]; fU1[3] += s_part[w2][3][ln];
      fU2[0] += s_part[w2][4][ln]; fU2[1] += s_part[w2][5][ln];
      fU2[2] += s_part[w2][6][ln]; fU2[3] += s_part[w2][7][ln];
      fRS    += s_part[w2][8][ln];
    }
    __syncthreads();   // protect s_part before next iteration's writes

    // ---- stats (redundant in every wave; lane (x,j) owns p = x*4+z) ----
    const float inv = 1.f / (fRS + EM_EPS);
    const float Cc  = fRS * inv;
    float lsum_p = 0.f;
    #pragma unroll
    for (int z = 0; z < 4; ++z) {
      mu[z] = fU1[z] * inv;
      float s2 = fU2[z] * inv - mu[z] * mu[z] * (2.f - Cc);
      s2 = fmaxf(s2, 0.f) + EM_EPS;
      i2s[z] = 0.5f / s2;
      lsum_p += __logf(s2);
    }
    float cap  = 4.f * bu_j + 0.5f * lsum_p;
    float lsum = lsum_p;
    cap += __shfl_xor(cap, 16); lsum += __shfl_xor(lsum, 16);
    cap += __shfl_xor(cap, 32); lsum += __shfl_xor(lsum, 32);
    const float cost = cap * fRS;
    const float aout = 1.f / (1.f + __expf(-(lam * (ba_j - cost))));
    L0   = -0.5f * (16.f * LOG2PI + lsum);
    loga = __logf(aout + EM_EPS);

    if (it == 2 && wv == 0 && jvalid) {
      if (x == 0) aout_g[((b * B + j) * OH + oy) * OW + ox] = aout;
      if (pose_out_g) {
        #pragma unroll
        for (int z = 0; z < 4; ++z)
          pose_out_g[((b * (B * 16) + j * 16 + x * 4 + z) * OH + oy) * OW + ox] = mu[z];
      }
    }
  }
}

// ---------------- spatial mean ----------------
__global__ __launch_bounds__(64) void k_mean(const float* __restrict__ a4,
                                             float* __restrict__ out) {
  int idx = blockIdx.x * 64 + threadIdx.x;
  if (idx >= 320) return;
  const float* pa = a4 + idx * 25;
  float s = 0.f;
  #pragma unroll
  for (int i = 0; i < 25; ++i) s += pa[i];
  out[idx] = s * (1.f / 25.f);
}

extern "C" void kernel_launch(void* const* d_in, const int* in_sizes, int n_in,
                              void* d_out, int out_size, void* d_ws, size_t ws_size,
                              hipStream_t stream) {
  const float* x       = (const float*)d_in[0];
  const float* conv1_w = (const float*)d_in[1];
  const float* bn1_g   = (const float*)d_in[2];
  const float* bn1_b   = (const float*)d_in[3];
  const float* conva_w = (const float*)d_in[4];
  const float* bna_g   = (const float*)d_in[5];
  const float* bna_b   = (const float*)d_in[6];
  const float* convp_w = (const float*)d_in[7];
  const float* bnp_g   = (const float*)d_in[8];
  const float* bnp_b   = (const float*)d_in[9];
  const float* W1      = (const float*)d_in[10];
  const float* bu1     = (const float*)d_in[11];
  const float* ba1     = (const float*)d_in[12];
  const float* bnc1_g  = (const float*)d_in[13];
  const float* bnc1_b  = (const float*)d_in[14];
  const float* W2      = (const float*)d_in[15];
  const float* bu2     = (const float*)d_in[16];
  const float* ba2     = (const float*)d_in[17];
  const float* bnc2_g  = (const float*)d_in[18];
  const float* bnc2_b  = (const float*)d_in[19];
  const float* Wfc     = (const float*)d_in[20];
  const float* bufc    = (const float*)d_in[21];
  const float* bafc    = (const float*)d_in[22];

  float* ws    = (float*)d_ws;
  float* out1  = ws;                          // 32*256*14*14
  float* a1    = out1  + 32 * 256 * 14 * 14;
  float* pose1 = a1    + 32 * 16 * 12 * 12;
  float* a2    = pose1 + 32 * 256 * 12 * 12;
  float* pose2 = a2    + 32 * 16 * 6 * 6;
  float* a3    = pose2 + 32 * 256 * 6 * 6;
  float* pose3 = a3    + 32 * 16 * 6 * 6;
  float* a4    = pose3 + 32 * 256 * 6 * 6;

  k_conv1<<<6272, 256, 0, stream>>>(x, conv1_w, bn1_g, bn1_b, out1);
  k_conv2<<<288, 192, 0, stream>>>(out1, conva_w, convp_w, bna_g, bna_b,
                                   bnp_g, bnp_b, a1, pose1);
  k_routing<3, 2, 1, 12, 12, 6, 6, 16><<<32 * 36, 256, 0, stream>>>(
      a1, pose1, W1, bu1, ba1, nullptr, nullptr, a2, pose2);
  k_routing<3, 1, 1, 6, 6, 6, 6, 16><<<32 * 36, 256, 0, stream>>>(
      a2, pose2, W2, bu2, ba2, bnc1_g, bnc1_b, a3, pose3);
  k_routing<4, 1, 1, 6, 6, 5, 5, 10><<<32 * 25, 256, 0, stream>>>(
      a3, pose3, Wfc, bufc, bafc, bnc2_g, bnc2_b, a4, nullptr);
  k_mean<<<5, 64, 0, stream>>>(a4, (float*)d_out);
}

// Round 4
// 612.749 us; speedup vs baseline: 2.8160x; 1.2108x over previous
//
#include <hip/hip_runtime.h>
#include <math.h>

#define EM_EPS 1e-8f
#define BN_SC 0.999995000037f   // 1/sqrt(1+1e-5)
#define LOG2PI 1.8378770664093453f

// ---------------- conv1 (5x5 s2 VALID) + bn1 ----------------
// x (32,3,32,32), w (256,3,5,5) -> out (32,256,14,14)
__global__ __launch_bounds__(256) void k_conv1(
    const float* __restrict__ x, const float* __restrict__ w,
    const float* __restrict__ g, const float* __restrict__ bb,
    float* __restrict__ out) {
  int idx = blockIdx.x * 256 + threadIdx.x;
  int ox = idx % 14; int t = idx / 14;
  int oy = t % 14; t /= 14;
  int co = t % 256; int b = t / 256;
  const float* xb = x + b * 3 * 1024;
  const float* wc = w + co * 75;
  float acc = 0.f;
  #pragma unroll
  for (int ci = 0; ci < 3; ++ci) {
    const float* xc = xb + ci * 1024 + (oy * 2) * 32 + ox * 2;
    const float* wk = wc + ci * 25;
    #pragma unroll
    for (int kh = 0; kh < 5; ++kh)
      #pragma unroll
      for (int kw = 0; kw < 5; ++kw)
        acc = fmaf(xc[kh * 32 + kw], wk[kh * 5 + kw], acc);
  }
  out[idx] = acc * (g[co] * BN_SC) + bb[co];
}

// ------------- conv2 partial (K-split over 4 blocks) -------------
// grid = 32 b x 9 co-groups x 4 k-chunks; 192 thr = 12 rows x 16 co-pairs.
// Each block accumulates 4 of the 16 ci-chunks, writes raw partials to ws.
__global__ __launch_bounds__(192) void k_conv2_part(
    const float* __restrict__ in,
    const float* __restrict__ wa, const float* __restrict__ wp,
    float* __restrict__ partial) {
  __shared__ float s_in[16 * 14 * 16];   // [ci][iy][ix pad16]
  __shared__ float s_w[16 * 9 * 34];     // [ci][tap][co pad34]

  const int t   = threadIdx.x;
  const int row = t >> 4;
  const int cg  = t & 15;
  const int b   = blockIdx.x / 36;
  const int r36 = blockIdx.x % 36;
  const int gco = (r36 >> 2) * 32;
  const int kc  = r36 & 3;
  const float* inb = in + b * 50176;

  float acc[2][12];
  #pragma unroll
  for (int u = 0; u < 2; ++u)
    #pragma unroll
    for (int px = 0; px < 12; ++px) acc[u][px] = 0.f;

  for (int ch = kc * 4; ch < kc * 4 + 4; ++ch) {
    __syncthreads();
    for (int idx = t; idx < 3136; idx += 192) {
      int ci = idx / 196, r = idx - ci * 196;
      int iy = r / 14, ix = r - iy * 14;
      s_in[ci * 224 + iy * 16 + ix] = inb[ch * 3136 + idx];
    }
    for (int idx = t; idx < 4608; idx += 192) {
      int co = idx / 144, rem = idx - co * 144;
      int c = gco + co;
      float val = 0.f;
      if (c < 272) {
        const float* wrow = (c < 16) ? (wa + c * 2304) : (wp + (c - 16) * 2304);
        val = wrow[ch * 144 + rem];
      }
      s_w[rem * 34 + co] = val;
    }
    __syncthreads();

    for (int ci = 0; ci < 16; ++ci) {
      float rin[3][16];
      #pragma unroll
      for (int kh = 0; kh < 3; ++kh) {
        const float4* rp = (const float4*)&s_in[ci * 224 + (row + kh) * 16];
        #pragma unroll
        for (int x = 0; x < 4; ++x)
          *(float4*)&rin[kh][x * 4] = rp[x];
      }
      #pragma unroll
      for (int kh = 0; kh < 3; ++kh) {
        #pragma unroll
        for (int kw = 0; kw < 3; ++kw) {
          float2 wv = *(const float2*)&s_w[(ci * 9 + kh * 3 + kw) * 34 + cg * 2];
          #pragma unroll
          for (int px = 0; px < 12; ++px) {
            float iv = rin[kh][px + kw];
            acc[0][px] = fmaf(iv, wv.x, acc[0][px]);
            acc[1][px] = fmaf(iv, wv.y, acc[1][px]);
          }
        }
      }
    }
  }

  // write partials: P[((kc*32 + b)*288 + co)*144 + px]
  #pragma unroll
  for (int u = 0; u < 2; ++u) {
    int c = gco + cg * 2 + u;
    float* dst = partial + ((size_t)(kc * 32 + b) * 288 + c) * 144 + row * 12;
    #pragma unroll
    for (int px = 0; px < 12; ++px) dst[px] = acc[u][px];
  }
}

// ------------- conv2 reduce: sum 4 partials + bn (+sigmoid for a) -------------
__global__ __launch_bounds__(256) void k_conv2_red(
    const float* __restrict__ partial,
    const float* __restrict__ ga, const float* __restrict__ bba,
    const float* __restrict__ gp, const float* __restrict__ bbp,
    float* __restrict__ a1, float* __restrict__ pose1) {
  int idx = blockIdx.x * 256 + threadIdx.x;
  if (idx >= 32 * 272 * 144) return;
  int px = idx % 144; int r = idx / 144;
  int c = r % 272; int b = r / 272;
  const size_t base = ((size_t)b * 288 + c) * 144 + px;
  const size_t kstr = (size_t)32 * 288 * 144;
  float s = partial[base] + partial[base + kstr]
          + partial[base + 2 * kstr] + partial[base + 3 * kstr];
  if (c < 16) {
    float v = s * (ga[c] * BN_SC) + bba[c];
    a1[((size_t)b * 16 + c) * 144 + px] = 1.f / (1.f + expf(-v));
  } else {
    int cp = c - 16;
    pose1[((size_t)b * 256 + cp) * 144 + px] = s * (gp[cp] * BN_SC) + bbp[cp];
  }
}

// ------------- conv2 single-pass fallback (ws too small) -------------
__global__ __launch_bounds__(192) void k_conv2(
    const float* __restrict__ in,
    const float* __restrict__ wa, const float* __restrict__ wp,
    const float* __restrict__ ga, const float* __restrict__ bba,
    const float* __restrict__ gp, const float* __restrict__ bbp,
    float* __restrict__ a1, float* __restrict__ pose1) {
  __shared__ float s_in[16 * 14 * 16];
  __shared__ float s_w[16 * 9 * 34];

  const int t   = threadIdx.x;
  const int row = t >> 4;
  const int cg  = t & 15;
  const int b   = blockIdx.x / 9;
  const int gco = (blockIdx.x % 9) * 32;
  const float* inb = in + b * 50176;

  float acc[2][12];
  #pragma unroll
  for (int u = 0; u < 2; ++u)
    #pragma unroll
    for (int px = 0; px < 12; ++px) acc[u][px] = 0.f;

  for (int ch = 0; ch < 16; ++ch) {
    __syncthreads();
    for (int idx = t; idx < 3136; idx += 192) {
      int ci = idx / 196, r = idx - ci * 196;
      int iy = r / 14, ix = r - iy * 14;
      s_in[ci * 224 + iy * 16 + ix] = inb[ch * 3136 + idx];
    }
    for (int idx = t; idx < 4608; idx += 192) {
      int co = idx / 144, rem = idx - co * 144;
      int c = gco + co;
      float val = 0.f;
      if (c < 272) {
        const float* wrow = (c < 16) ? (wa + c * 2304) : (wp + (c - 16) * 2304);
        val = wrow[ch * 144 + rem];
      }
      s_w[rem * 34 + co] = val;
    }
    __syncthreads();

    for (int ci = 0; ci < 16; ++ci) {
      float rin[3][16];
      #pragma unroll
      for (int kh = 0; kh < 3; ++kh) {
        const float4* rp = (const float4*)&s_in[ci * 224 + (row + kh) * 16];
        #pragma unroll
        for (int x = 0; x < 4; ++x)
          *(float4*)&rin[kh][x * 4] = rp[x];
      }
      #pragma unroll
      for (int kh = 0; kh < 3; ++kh) {
        #pragma unroll
        for (int kw = 0; kw < 3; ++kw) {
          float2 wv = *(const float2*)&s_w[(ci * 9 + kh * 3 + kw) * 34 + cg * 2];
          #pragma unroll
          for (int px = 0; px < 12; ++px) {
            float iv = rin[kh][px + kw];
            acc[0][px] = fmaf(iv, wv.x, acc[0][px]);
            acc[1][px] = fmaf(iv, wv.y, acc[1][px]);
          }
        }
      }
    }
  }

  #pragma unroll
  for (int u = 0; u < 2; ++u) {
    int c = gco + cg * 2 + u;
    if (c >= 272) continue;
    if (c < 16) {
      float g_ = ga[c] * BN_SC, b_ = bba[c];
      float* dst = a1 + ((b * 16 + c) * 12 + row) * 12;
      #pragma unroll
      for (int px = 0; px < 12; ++px) {
        float v = acc[u][px] * g_ + b_;
        dst[px] = 1.f / (1.f + expf(-v));
      }
    } else {
      int cp = c - 16;
      float g_ = gp[cp] * BN_SC, b_ = bbp[cp];
      float* dst = pose1 + ((b * 256 + cp) * 12 + row) * 12;
      #pragma unroll
      for (int px = 0; px < 12; ++px)
        dst[px] = acc[u][px] * g_ + b_;
    }
  }
}

// ---------------- EM routing: block = one (b, output pixel) ----------------
template<int K, int S, int P, int HIN, int WIN, int OH, int OW, int B>
__global__ __launch_bounds__(256) void k_routing(
    const float* __restrict__ ag,      // (b,16,HIN,WIN)
    const float* __restrict__ poseg,   // (b,256,HIN,WIN)
    const float* __restrict__ Wg,      // (KKA,B,4,4)
    const float* __restrict__ bu, const float* __restrict__ ba,
    const float* __restrict__ bng, const float* __restrict__ bnb,
    float* __restrict__ aout_g,        // (b,B,OH,OW)
    float* __restrict__ pose_out_g) {  // (b,B*16,OH,OW) or null
  constexpr int A = 16;
  constexpr int KK = K * K;
  constexpr int KKA = KK * A;
  constexpr int KPW = KKA / 4;
  static_assert(KKA % 4 == 0, "KKA%4");

  __shared__ __attribute__((aligned(16))) float s_pp[KKA * 16];
  __shared__ float s_ain[KKA];
  __shared__ float s_part[4][9][64];

  const int t  = threadIdx.x;
  const int wv = t >> 6;
  const int ln = t & 63;
  const int x  = ln >> 4;
  const int j  = ln & 15;
  const int jc = (j < B) ? j : 0;
  const bool jvalid = (j < B);

  const int bi = blockIdx.x;
  const int b  = bi / (OH * OW);
  const int l  = bi % (OH * OW);
  const int oy = l / OW, ox = l % OW;

  for (int idx = t; idx < KKA * 16; idx += 256) {
    int k = idx >> 4, pe = idx & 15;
    int acap = k & 15, kki = k >> 4;
    int kh = kki / K, kw = kki % K;
    int iy = oy * S - P + kh, ix = ox * S - P + kw;
    float val = 0.f;
    if (iy >= 0 && iy < HIN && ix >= 0 && ix < WIN) {
      int c = acap * 16 + pe;
      val = poseg[((b * 256 + c) * HIN + iy) * WIN + ix];
      if (bng) val = val * (bng[c] * BN_SC) + bnb[c];
    }
    s_pp[idx] = val;
  }
  for (int k = t; k < KKA; k += 256) {
    int acap = k & 15, kki = k >> 4;
    int kh = kki / K, kw = kki % K;
    int iy = oy * S - P + kh, ix = ox * S - P + kw;
    float val = 0.f;
    if (iy >= 0 && iy < HIN && ix >= 0 && ix < WIN)
      val = ag[((b * A + acap) * HIN + iy) * WIN + ix];
    s_ain[k] = val;
  }
  __syncthreads();

  const float bu_j = bu[jc];
  const float ba_j = ba[jc];
  const int k0 = wv * KPW;

  float mu[4] = {0, 0, 0, 0}, i2s[4] = {0, 0, 0, 0};
  float L0 = 0.f, loga = 0.f;

  float p95 = 0.95f;
  for (int it = 0; it < 3; ++it) {
    const float lam = 0.01f * (1.0f - p95);
    p95 *= 0.95f;
    float U1[4] = {0, 0, 0, 0}, U2[4] = {0, 0, 0, 0}, RS = 0.f;

    for (int kk2 = 0; kk2 < KPW; ++kk2) {
      const int k = k0 + kk2;
      const float4 pp4 = *(const float4*)&s_pp[k * 16 + x * 4];
      const float* wr = Wg + (size_t)(k * B + jc) * 16;
      const float4 w0 = *(const float4*)(wr);
      const float4 w1 = *(const float4*)(wr + 4);
      const float4 w2 = *(const float4*)(wr + 8);
      const float4 w3 = *(const float4*)(wr + 12);
      float v0 = pp4.x * w0.x + pp4.y * w1.x + pp4.z * w2.x + pp4.w * w3.x;
      float v1 = pp4.x * w0.y + pp4.y * w1.y + pp4.z * w2.y + pp4.w * w3.y;
      float v2 = pp4.x * w0.z + pp4.y * w1.z + pp4.z * w2.z + pp4.w * w3.z;
      float v3 = pp4.x * w0.w + pp4.y * w1.w + pp4.z * w2.w + pp4.w * w3.w;
      const float ain = s_ain[k];
      float r;
      if (it == 0) {
        r = 1.0f / (float)B;
      } else {
        float d0 = v0 - mu[0], d1 = v1 - mu[1];
        float d2 = v2 - mu[2], d3 = v3 - mu[3];
        float s = d0 * d0 * i2s[0] + d1 * d1 * i2s[1]
                + d2 * d2 * i2s[2] + d3 * d3 * i2s[3];
        s += __shfl_xor(s, 16); s += __shfl_xor(s, 32);   // sum over p
        float lnp = L0 + loga - s;
        if (!jvalid) lnp = -1e30f;
        float mx = lnp;
        mx = fmaxf(mx, __shfl_xor(mx, 1));
        mx = fmaxf(mx, __shfl_xor(mx, 2));
        mx = fmaxf(mx, __shfl_xor(mx, 4));
        mx = fmaxf(mx, __shfl_xor(mx, 8));
        float e = __expf(lnp - mx);
        float sm = e;
        sm += __shfl_xor(sm, 1); sm += __shfl_xor(sm, 2);
        sm += __shfl_xor(sm, 4); sm += __shfl_xor(sm, 8);
        r = e * __builtin_amdgcn_rcpf(sm);
      }
      float ra = r * ain;
      RS += ra;
      float t0 = ra * v0, t1 = ra * v1, t2 = ra * v2, t3 = ra * v3;
      U1[0] += t0; U1[1] += t1; U1[2] += t2; U1[3] += t3;
      U2[0] += t0 * v0; U2[1] += t1 * v1; U2[2] += t2 * v2; U2[3] += t3 * v3;
    }

    s_part[wv][0][ln] = U1[0]; s_part[wv][1][ln] = U1[1];
    s_part[wv][2][ln] = U1[2]; s_part[wv][3][ln] = U1[3];
    s_part[wv][4][ln] = U2[0]; s_part[wv][5][ln] = U2[1];
    s_part[wv][6][ln] = U2[2]; s_part[wv][7][ln] = U2[3];
    s_part[wv][8][ln] = RS;
    __syncthreads();
    float fU1[4] = {0, 0, 0, 0}, fU2[4] = {0, 0, 0, 0}, fRS = 0.f;
    #pragma unroll
    for (int w2 = 0; w2 < 4; ++w2) {
      fU1[0] += s_part[w2][0][ln]; fU1[1] += s_part[w2][1][ln];
      fU1[2] += s_part[w2][2][ln]; fU1[3] += s_part[w2][3][ln];
      fU2[0] += s_part[w2][4][ln]; fU2[1] += s_part[w2][5][ln];
      fU2[2] += s_part[w2][6][ln]; fU2[3] += s_part[w2][7][ln];
      fRS    += s_part[w2][8][ln];
    }
    __syncthreads();

    const float inv = 1.f / (fRS + EM_EPS);
    const float Cc  = fRS * inv;
    float lsum_p = 0.f;
    #pragma unroll
    for (int z = 0; z < 4; ++z) {
      mu[z] = fU1[z] * inv;
      float s2 = fU2[z] * inv - mu[z] * mu[z] * (2.f - Cc);
      s2 = fmaxf(s2, 0.f) + EM_EPS;
      i2s[z] = 0.5f / s2;
      lsum_p += __logf(s2);
    }
    float cap  = 4.f * bu_j + 0.5f * lsum_p;
    float lsum = lsum_p;
    cap += __shfl_xor(cap, 16); lsum += __shfl_xor(lsum, 16);
    cap += __shfl_xor(cap, 32); lsum += __shfl_xor(lsum, 32);
    const float cost = cap * fRS;
    const float aout = 1.f / (1.f + __expf(-(lam * (ba_j - cost))));
    L0   = -0.5f * (16.f * LOG2PI + lsum);
    loga = __logf(aout + EM_EPS);

    if (it == 2 && wv == 0 && jvalid) {
      if (x == 0) aout_g[((b * B + j) * OH + oy) * OW + ox] = aout;
      if (pose_out_g) {
        #pragma unroll
        for (int z = 0; z < 4; ++z)
          pose_out_g[((b * (B * 16) + j * 16 + x * 4 + z) * OH + oy) * OW + ox] = mu[z];
      }
    }
  }
}

// ---------------- spatial mean ----------------
__global__ __launch_bounds__(64) void k_mean(const float* __restrict__ a4,
                                             float* __restrict__ out) {
  int idx = blockIdx.x * 64 + threadIdx.x;
  if (idx >= 320) return;
  const float* pa = a4 + idx * 25;
  float s = 0.f;
  #pragma unroll
  for (int i = 0; i < 25; ++i) s += pa[i];
  out[idx] = s * (1.f / 25.f);
}

extern "C" void kernel_launch(void* const* d_in, const int* in_sizes, int n_in,
                              void* d_out, int out_size, void* d_ws, size_t ws_size,
                              hipStream_t stream) {
  const float* x       = (const float*)d_in[0];
  const float* conv1_w = (const float*)d_in[1];
  const float* bn1_g   = (const float*)d_in[2];
  const float* bn1_b   = (const float*)d_in[3];
  const float* conva_w = (const float*)d_in[4];
  const float* bna_g   = (const float*)d_in[5];
  const float* bna_b   = (const float*)d_in[6];
  const float* convp_w = (const float*)d_in[7];
  const float* bnp_g   = (const float*)d_in[8];
  const float* bnp_b   = (const float*)d_in[9];
  const float* W1      = (const float*)d_in[10];
  const float* bu1     = (const float*)d_in[11];
  const float* ba1     = (const float*)d_in[12];
  const float* bnc1_g  = (const float*)d_in[13];
  const float* bnc1_b  = (const float*)d_in[14];
  const float* W2      = (const float*)d_in[15];
  const float* bu2     = (const float*)d_in[16];
  const float* ba2     = (const float*)d_in[17];
  const float* bnc2_g  = (const float*)d_in[18];
  const float* bnc2_b  = (const float*)d_in[19];
  const float* Wfc     = (const float*)d_in[20];
  const float* bufc    = (const float*)d_in[21];
  const float* bafc    = (const float*)d_in[22];

  float* ws    = (float*)d_ws;
  float* out1  = ws;                          // 32*256*14*14 = 1605632
  float* a1    = out1  + 32 * 256 * 14 * 14;  // 73728
  float* pose1 = a1    + 32 * 16 * 12 * 12;   // 1179648
  float* a2    = pose1 + 32 * 256 * 12 * 12;  // 18432
  float* pose2 = a2    + 32 * 16 * 6 * 6;     // 294912
  float* a3    = pose2 + 32 * 256 * 6 * 6;    // 18432
  float* pose3 = a3    + 32 * 16 * 6 * 6;     // 294912
  float* a4    = pose3 + 32 * 256 * 6 * 6;    // 8000
  float* partial = a4  + 8000;                // 4*32*288*144 = 5308416
  const size_t base_floats = 3493696;
  const size_t need = (base_floats + (size_t)4 * 32 * 288 * 144) * 4;

  k_conv1<<<6272, 256, 0, stream>>>(x, conv1_w, bn1_g, bn1_b, out1);
  if (ws_size >= need) {
    k_conv2_part<<<1152, 192, 0, stream>>>(out1, conva_w, convp_w, partial);
    k_conv2_red<<<4896, 256, 0, stream>>>(partial, bna_g, bna_b, bnp_g, bnp_b,
                                          a1, pose1);
  } else {
    k_conv2<<<288, 192, 0, stream>>>(out1, conva_w, convp_w, bna_g, bna_b,
                                     bnp_g, bnp_b, a1, pose1);
  }
  k_routing<3, 2, 1, 12, 12, 6, 6, 16><<<32 * 36, 256, 0, stream>>>(
      a1, pose1, W1, bu1, ba1, nullptr, nullptr, a2, pose2);
  k_routing<3, 1, 1, 6, 6, 6, 6, 16><<<32 * 36, 256, 0, stream>>>(
      a2, pose2, W2, bu2, ba2, bnc1_g, bnc1_b, a3, pose3);
  k_routing<4, 1, 1, 6, 6, 5, 5, 10><<<32 * 25, 256, 0, stream>>>(
      a3, pose3, Wfc, bufc, bafc, bnc2_g, bnc2_b, a4, nullptr);
  k_mean<<<5, 64, 0, stream>>>(a4, (float*)d_out);
}

// Round 5
// 605.844 us; speedup vs baseline: 2.8481x; 1.0114x over previous
//
#include <hip/hip_runtime.h>
#include <math.h>

#define EM_EPS 1e-8f
#define BN_SC 0.999995000037f   // 1/sqrt(1+1e-5)
#define LOG2PI 1.8378770664093453f

// ---------------- conv1 (5x5 s2 VALID) + bn1 ----------------
// x (32,3,32,32), w (256,3,5,5) -> out (32,256,14,14)
__global__ __launch_bounds__(256) void k_conv1(
    const float* __restrict__ x, const float* __restrict__ w,
    const float* __restrict__ g, const float* __restrict__ bb,
    float* __restrict__ out) {
  int idx = blockIdx.x * 256 + threadIdx.x;
  int ox = idx % 14; int t = idx / 14;
  int oy = t % 14; t /= 14;
  int co = t % 256; int b = t / 256;
  const float* xb = x + b * 3 * 1024;
  const float* wc = w + co * 75;
  float acc = 0.f;
  #pragma unroll
  for (int ci = 0; ci < 3; ++ci) {
    const float* xc = xb + ci * 1024 + (oy * 2) * 32 + ox * 2;
    const float* wk = wc + ci * 25;
    #pragma unroll
    for (int kh = 0; kh < 5; ++kh)
      #pragma unroll
      for (int kw = 0; kw < 5; ++kw)
        acc = fmaf(xc[kh * 32 + kw], wk[kh * 5 + kw], acc);
  }
  out[idx] = acc * (g[co] * BN_SC) + bb[co];
}

// ------------- conv2 partial (K-split over 4 blocks) -------------
__global__ __launch_bounds__(192) void k_conv2_part(
    const float* __restrict__ in,
    const float* __restrict__ wa, const float* __restrict__ wp,
    float* __restrict__ partial) {
  __shared__ float s_in[16 * 14 * 16];   // [ci][iy][ix pad16]
  __shared__ float s_w[16 * 9 * 34];     // [ci][tap][co pad34]

  const int t   = threadIdx.x;
  const int row = t >> 4;
  const int cg  = t & 15;
  const int b   = blockIdx.x / 36;
  const int r36 = blockIdx.x % 36;
  const int gco = (r36 >> 2) * 32;
  const int kc  = r36 & 3;
  const float* inb = in + b * 50176;

  float acc[2][12];
  #pragma unroll
  for (int u = 0; u < 2; ++u)
    #pragma unroll
    for (int px = 0; px < 12; ++px) acc[u][px] = 0.f;

  for (int ch = kc * 4; ch < kc * 4 + 4; ++ch) {
    __syncthreads();
    for (int idx = t; idx < 3136; idx += 192) {
      int ci = idx / 196, r = idx - ci * 196;
      int iy = r / 14, ix = r - iy * 14;
      s_in[ci * 224 + iy * 16 + ix] = inb[ch * 3136 + idx];
    }
    for (int idx = t; idx < 4608; idx += 192) {
      int co = idx / 144, rem = idx - co * 144;
      int c = gco + co;
      float val = 0.f;
      if (c < 272) {
        const float* wrow = (c < 16) ? (wa + c * 2304) : (wp + (c - 16) * 2304);
        val = wrow[ch * 144 + rem];
      }
      s_w[rem * 34 + co] = val;
    }
    __syncthreads();

    for (int ci = 0; ci < 16; ++ci) {
      float rin[3][16];
      #pragma unroll
      for (int kh = 0; kh < 3; ++kh) {
        const float4* rp = (const float4*)&s_in[ci * 224 + (row + kh) * 16];
        #pragma unroll
        for (int x = 0; x < 4; ++x)
          *(float4*)&rin[kh][x * 4] = rp[x];
      }
      #pragma unroll
      for (int kh = 0; kh < 3; ++kh) {
        #pragma unroll
        for (int kw = 0; kw < 3; ++kw) {
          float2 wv = *(const float2*)&s_w[(ci * 9 + kh * 3 + kw) * 34 + cg * 2];
          #pragma unroll
          for (int px = 0; px < 12; ++px) {
            float iv = rin[kh][px + kw];
            acc[0][px] = fmaf(iv, wv.x, acc[0][px]);
            acc[1][px] = fmaf(iv, wv.y, acc[1][px]);
          }
        }
      }
    }
  }

  #pragma unroll
  for (int u = 0; u < 2; ++u) {
    int c = gco + cg * 2 + u;
    float* dst = partial + ((size_t)(kc * 32 + b) * 288 + c) * 144 + row * 12;
    #pragma unroll
    for (int px = 0; px < 12; ++px) dst[px] = acc[u][px];
  }
}

// ------------- conv2 reduce: sum 4 partials + bn (+sigmoid for a) -------------
__global__ __launch_bounds__(256) void k_conv2_red(
    const float* __restrict__ partial,
    const float* __restrict__ ga, const float* __restrict__ bba,
    const float* __restrict__ gp, const float* __restrict__ bbp,
    float* __restrict__ a1, float* __restrict__ pose1) {
  int idx = blockIdx.x * 256 + threadIdx.x;
  if (idx >= 32 * 272 * 144) return;
  int px = idx % 144; int r = idx / 144;
  int c = r % 272; int b = r / 272;
  const size_t base = ((size_t)b * 288 + c) * 144 + px;
  const size_t kstr = (size_t)32 * 288 * 144;
  float s = partial[base] + partial[base + kstr]
          + partial[base + 2 * kstr] + partial[base + 3 * kstr];
  if (c < 16) {
    float v = s * (ga[c] * BN_SC) + bba[c];
    a1[((size_t)b * 16 + c) * 144 + px] = 1.f / (1.f + expf(-v));
  } else {
    int cp = c - 16;
    pose1[((size_t)b * 256 + cp) * 144 + px] = s * (gp[cp] * BN_SC) + bbp[cp];
  }
}

// ------------- conv2 single-pass fallback (ws too small) -------------
__global__ __launch_bounds__(192) void k_conv2(
    const float* __restrict__ in,
    const float* __restrict__ wa, const float* __restrict__ wp,
    const float* __restrict__ ga, const float* __restrict__ bba,
    const float* __restrict__ gp, const float* __restrict__ bbp,
    float* __restrict__ a1, float* __restrict__ pose1) {
  __shared__ float s_in[16 * 14 * 16];
  __shared__ float s_w[16 * 9 * 34];

  const int t   = threadIdx.x;
  const int row = t >> 4;
  const int cg  = t & 15;
  const int b   = blockIdx.x / 9;
  const int gco = (blockIdx.x % 9) * 32;
  const float* inb = in + b * 50176;

  float acc[2][12];
  #pragma unroll
  for (int u = 0; u < 2; ++u)
    #pragma unroll
    for (int px = 0; px < 12; ++px) acc[u][px] = 0.f;

  for (int ch = 0; ch < 16; ++ch) {
    __syncthreads();
    for (int idx = t; idx < 3136; idx += 192) {
      int ci = idx / 196, r = idx - ci * 196;
      int iy = r / 14, ix = r - iy * 14;
      s_in[ci * 224 + iy * 16 + ix] = inb[ch * 3136 + idx];
    }
    for (int idx = t; idx < 4608; idx += 192) {
      int co = idx / 144, rem = idx - co * 144;
      int c = gco + co;
      float val = 0.f;
      if (c < 272) {
        const float* wrow = (c < 16) ? (wa + c * 2304) : (wp + (c - 16) * 2304);
        val = wrow[ch * 144 + rem];
      }
      s_w[rem * 34 + co] = val;
    }
    __syncthreads();

    for (int ci = 0; ci < 16; ++ci) {
      float rin[3][16];
      #pragma unroll
      for (int kh = 0; kh < 3; ++kh) {
        const float4* rp = (const float4*)&s_in[ci * 224 + (row + kh) * 16];
        #pragma unroll
        for (int x = 0; x < 4; ++x)
          *(float4*)&rin[kh][x * 4] = rp[x];
      }
      #pragma unroll
      for (int kh = 0; kh < 3; ++kh) {
        #pragma unroll
        for (int kw = 0; kw < 3; ++kw) {
          float2 wv = *(const float2*)&s_w[(ci * 9 + kh * 3 + kw) * 34 + cg * 2];
          #pragma unroll
          for (int px = 0; px < 12; ++px) {
            float iv = rin[kh][px + kw];
            acc[0][px] = fmaf(iv, wv.x, acc[0][px]);
            acc[1][px] = fmaf(iv, wv.y, acc[1][px]);
          }
        }
      }
    }
  }

  #pragma unroll
  for (int u = 0; u < 2; ++u) {
    int c = gco + cg * 2 + u;
    if (c >= 272) continue;
    if (c < 16) {
      float g_ = ga[c] * BN_SC, b_ = bba[c];
      float* dst = a1 + ((b * 16 + c) * 12 + row) * 12;
      #pragma unroll
      for (int px = 0; px < 12; ++px) {
        float v = acc[u][px] * g_ + b_;
        dst[px] = 1.f / (1.f + expf(-v));
      }
    } else {
      int cp = c - 16;
      float g_ = gp[cp] * BN_SC, b_ = bbp[cp];
      float* dst = pose1 + ((b * 256 + cp) * 12 + row) * 12;
      #pragma unroll
      for (int px = 0; px < 12; ++px)
        dst[px] = acc[u][px] * g_ + b_;
    }
  }
}

// ---------------- EM routing: block = one (b, output pixel) ----------------
// 512 threads = 8 waves; wave w owns k in [w*KKA/8, (w+1)*KKA/8).
// lane = x*16 + j : x = pose row group, j = output capsule.
template<int K, int S, int P, int HIN, int WIN, int OH, int OW, int B>
__global__ __launch_bounds__(512, 4) void k_routing(
    const float* __restrict__ ag,      // (b,16,HIN,WIN)
    const float* __restrict__ poseg,   // (b,256,HIN,WIN)
    const float* __restrict__ Wg,      // (KKA,B,4,4)
    const float* __restrict__ bu, const float* __restrict__ ba,
    const float* __restrict__ bng, const float* __restrict__ bnb,
    float* __restrict__ aout_g,        // (b,B,OH,OW)
    float* __restrict__ pose_out_g) {  // (b,B*16,OH,OW) or null
  constexpr int A = 16;
  constexpr int KK = K * K;
  constexpr int KKA = KK * A;
  constexpr int NW = 8;
  constexpr int KPW = KKA / NW;
  static_assert(KKA % NW == 0, "KKA%NW");

  __shared__ __attribute__((aligned(16))) float s_pp[KKA * 16];
  __shared__ float s_ain[KKA];
  __shared__ float4 sU1[NW][64];
  __shared__ float4 sU2[NW][64];
  __shared__ float  sRS[NW][64];

  const int t  = threadIdx.x;
  const int wv = t >> 6;
  const int ln = t & 63;
  const int x  = ln >> 4;
  const int j  = ln & 15;
  const int jc = (j < B) ? j : 0;
  const bool jvalid = (j < B);

  const int bi = blockIdx.x;
  const int b  = bi / (OH * OW);
  const int l  = bi % (OH * OW);
  const int oy = l / OW, ox = l % OW;

  for (int idx = t; idx < KKA * 16; idx += 512) {
    int k = idx >> 4, pe = idx & 15;
    int acap = k & 15, kki = k >> 4;
    int kh = kki / K, kw = kki % K;
    int iy = oy * S - P + kh, ix = ox * S - P + kw;
    float val = 0.f;
    if (iy >= 0 && iy < HIN && ix >= 0 && ix < WIN) {
      int c = acap * 16 + pe;
      val = poseg[((b * 256 + c) * HIN + iy) * WIN + ix];
      if (bng) val = val * (bng[c] * BN_SC) + bnb[c];
    }
    s_pp[idx] = val;
  }
  for (int k = t; k < KKA; k += 512) {
    int acap = k & 15, kki = k >> 4;
    int kh = kki / K, kw = kki % K;
    int iy = oy * S - P + kh, ix = ox * S - P + kw;
    float val = 0.f;
    if (iy >= 0 && iy < HIN && ix >= 0 && ix < WIN)
      val = ag[((b * A + acap) * HIN + iy) * WIN + ix];
    s_ain[k] = val;
  }
  __syncthreads();

  const float bu_j = bu[jc];
  const float ba_j = ba[jc];
  const int k0 = wv * KPW;

  float mu[4] = {0, 0, 0, 0}, i2s[4] = {0, 0, 0, 0};
  float L0 = 0.f, loga = 0.f;

  float p95 = 0.95f;
  for (int it = 0; it < 3; ++it) {
    const float lam = 0.01f * (1.0f - p95);
    p95 *= 0.95f;
    float U1[4] = {0, 0, 0, 0}, U2[4] = {0, 0, 0, 0}, RS = 0.f;

    if (it == 0) {
      #pragma unroll 4
      for (int kk2 = 0; kk2 < KPW; ++kk2) {
        const int k = k0 + kk2;
        const float4 pp4 = *(const float4*)&s_pp[k * 16 + x * 4];
        const float* wr = Wg + (size_t)(k * B + jc) * 16;
        const float4 w0 = *(const float4*)(wr);
        const float4 w1 = *(const float4*)(wr + 4);
        const float4 w2 = *(const float4*)(wr + 8);
        const float4 w3 = *(const float4*)(wr + 12);
        float v0 = pp4.x * w0.x + pp4.y * w1.x + pp4.z * w2.x + pp4.w * w3.x;
        float v1 = pp4.x * w0.y + pp4.y * w1.y + pp4.z * w2.y + pp4.w * w3.y;
        float v2 = pp4.x * w0.z + pp4.y * w1.z + pp4.z * w2.z + pp4.w * w3.z;
        float v3 = pp4.x * w0.w + pp4.y * w1.w + pp4.z * w2.w + pp4.w * w3.w;
        float ra = s_ain[k] * (1.0f / (float)B);
        RS += ra;
        float t0 = ra * v0, t1 = ra * v1, t2 = ra * v2, t3 = ra * v3;
        U1[0] += t0; U1[1] += t1; U1[2] += t2; U1[3] += t3;
        U2[0] += t0 * v0; U2[1] += t1 * v1; U2[2] += t2 * v2; U2[3] += t3 * v3;
      }
    } else {
      #pragma unroll 2
      for (int kk2 = 0; kk2 < KPW; ++kk2) {
        const int k = k0 + kk2;
        const float4 pp4 = *(const float4*)&s_pp[k * 16 + x * 4];
        const float* wr = Wg + (size_t)(k * B + jc) * 16;
        const float4 w0 = *(const float4*)(wr);
        const float4 w1 = *(const float4*)(wr + 4);
        const float4 w2 = *(const float4*)(wr + 8);
        const float4 w3 = *(const float4*)(wr + 12);
        float v0 = pp4.x * w0.x + pp4.y * w1.x + pp4.z * w2.x + pp4.w * w3.x;
        float v1 = pp4.x * w0.y + pp4.y * w1.y + pp4.z * w2.y + pp4.w * w3.y;
        float v2 = pp4.x * w0.z + pp4.y * w1.z + pp4.z * w2.z + pp4.w * w3.z;
        float v3 = pp4.x * w0.w + pp4.y * w1.w + pp4.z * w2.w + pp4.w * w3.w;
        float d0 = v0 - mu[0], d1 = v1 - mu[1];
        float d2 = v2 - mu[2], d3 = v3 - mu[3];
        float s = d0 * d0 * i2s[0] + d1 * d1 * i2s[1]
                + d2 * d2 * i2s[2] + d3 * d3 * i2s[3];
        s += __shfl_xor(s, 16); s += __shfl_xor(s, 32);   // sum over p
        float lnp = L0 + loga - s;
        if (!jvalid) lnp = -1e30f;
        float mx = lnp;
        mx = fmaxf(mx, __shfl_xor(mx, 1));
        mx = fmaxf(mx, __shfl_xor(mx, 2));
        mx = fmaxf(mx, __shfl_xor(mx, 4));
        mx = fmaxf(mx, __shfl_xor(mx, 8));
        float e = __expf(lnp - mx);
        float sm = e;
        sm += __shfl_xor(sm, 1); sm += __shfl_xor(sm, 2);
        sm += __shfl_xor(sm, 4); sm += __shfl_xor(sm, 8);
        float ra = e * __builtin_amdgcn_rcpf(sm) * s_ain[k];
        RS += ra;
        float t0 = ra * v0, t1 = ra * v1, t2 = ra * v2, t3 = ra * v3;
        U1[0] += t0; U1[1] += t1; U1[2] += t2; U1[3] += t3;
        U2[0] += t0 * v0; U2[1] += t1 * v1; U2[2] += t2 * v2; U2[3] += t3 * v3;
      }
    }

    // ---- cross-wave reduction over the 8 k-partitions ----
    sU1[wv][ln] = make_float4(U1[0], U1[1], U1[2], U1[3]);
    sU2[wv][ln] = make_float4(U2[0], U2[1], U2[2], U2[3]);
    sRS[wv][ln] = RS;
    __syncthreads();
    float fU1[4] = {0, 0, 0, 0}, fU2[4] = {0, 0, 0, 0}, fRS = 0.f;
    #pragma unroll
    for (int w2 = 0; w2 < NW; ++w2) {
      float4 a = sU1[w2][ln];
      float4 c = sU2[w2][ln];
      fU1[0] += a.x; fU1[1] += a.y; fU1[2] += a.z; fU1[3] += a.w;
      fU2[0] += c.x; fU2[1] += c.y; fU2[2] += c.z; fU2[3] += c.w;
      fRS    += sRS[w2][ln];
    }
    __syncthreads();   // protect partials before next iteration's writes

    const float inv = 1.f / (fRS + EM_EPS);
    const float Cc  = fRS * inv;
    float lsum_p = 0.f;
    #pragma unroll
    for (int z = 0; z < 4; ++z) {
      mu[z] = fU1[z] * inv;
      float s2 = fU2[z] * inv - mu[z] * mu[z] * (2.f - Cc);
      s2 = fmaxf(s2, 0.f) + EM_EPS;
      i2s[z] = 0.5f / s2;
      lsum_p += __logf(s2);
    }
    float cap  = 4.f * bu_j + 0.5f * lsum_p;
    float lsum = lsum_p;
    cap += __shfl_xor(cap, 16); lsum += __shfl_xor(lsum, 16);
    cap += __shfl_xor(cap, 32); lsum += __shfl_xor(lsum, 32);
    const float cost = cap * fRS;
    const float aout = 1.f / (1.f + __expf(-(lam * (ba_j - cost))));
    L0   = -0.5f * (16.f * LOG2PI + lsum);
    loga = __logf(aout + EM_EPS);

    if (it == 2 && wv == 0 && jvalid) {
      if (x == 0) aout_g[((b * B + j) * OH + oy) * OW + ox] = aout;
      if (pose_out_g) {
        #pragma unroll
        for (int z = 0; z < 4; ++z)
          pose_out_g[((b * (B * 16) + j * 16 + x * 4 + z) * OH + oy) * OW + ox] = mu[z];
      }
    }
  }
}

// ---------------- spatial mean ----------------
__global__ __launch_bounds__(64) void k_mean(const float* __restrict__ a4,
                                             float* __restrict__ out) {
  int idx = blockIdx.x * 64 + threadIdx.x;
  if (idx >= 320) return;
  const float* pa = a4 + idx * 25;
  float s = 0.f;
  #pragma unroll
  for (int i = 0; i < 25; ++i) s += pa[i];
  out[idx] = s * (1.f / 25.f);
}

extern "C" void kernel_launch(void* const* d_in, const int* in_sizes, int n_in,
                              void* d_out, int out_size, void* d_ws, size_t ws_size,
                              hipStream_t stream) {
  const float* x       = (const float*)d_in[0];
  const float* conv1_w = (const float*)d_in[1];
  const float* bn1_g   = (const float*)d_in[2];
  const float* bn1_b   = (const float*)d_in[3];
  const float* conva_w = (const float*)d_in[4];
  const float* bna_g   = (const float*)d_in[5];
  const float* bna_b   = (const float*)d_in[6];
  const float* convp_w = (const float*)d_in[7];
  const float* bnp_g   = (const float*)d_in[8];
  const float* bnp_b   = (const float*)d_in[9];
  const float* W1      = (const float*)d_in[10];
  const float* bu1     = (const float*)d_in[11];
  const float* ba1     = (const float*)d_in[12];
  const float* bnc1_g  = (const float*)d_in[13];
  const float* bnc1_b  = (const float*)d_in[14];
  const float* W2      = (const float*)d_in[15];
  const float* bu2     = (const float*)d_in[16];
  const float* ba2     = (const float*)d_in[17];
  const float* bnc2_g  = (const float*)d_in[18];
  const float* bnc2_b  = (const float*)d_in[19];
  const float* Wfc     = (const float*)d_in[20];
  const float* bufc    = (const float*)d_in[21];
  const float* bafc    = (const float*)d_in[22];

  float* ws    = (float*)d_ws;
  float* out1  = ws;                          // 32*256*14*14 = 1605632
  float* a1    = out1  + 32 * 256 * 14 * 14;  // 73728
  float* pose1 = a1    + 32 * 16 * 12 * 12;   // 1179648
  float* a2    = pose1 + 32 * 256 * 12 * 12;  // 18432
  float* pose2 = a2    + 32 * 16 * 6 * 6;     // 294912
  float* a3    = pose2 + 32 * 256 * 6 * 6;    // 18432
  float* pose3 = a3    + 32 * 16 * 6 * 6;     // 294912
  float* a4    = pose3 + 32 * 256 * 6 * 6;    // 8000
  float* partial = a4  + 8000;                // 4*32*288*144 = 5308416
  const size_t base_floats = 3493696;
  const size_t need = (base_floats + (size_t)4 * 32 * 288 * 144) * 4;

  k_conv1<<<6272, 256, 0, stream>>>(x, conv1_w, bn1_g, bn1_b, out1);
  if (ws_size >= need) {
    k_conv2_part<<<1152, 192, 0, stream>>>(out1, conva_w, convp_w, partial);
    k_conv2_red<<<4896, 256, 0, stream>>>(partial, bna_g, bna_b, bnp_g, bnp_b,
                                          a1, pose1);
  } else {
    k_conv2<<<288, 192, 0, stream>>>(out1, conva_w, convp_w, bna_g, bna_b,
                                     bnp_g, bnp_b, a1, pose1);
  }
  k_routing<3, 2, 1, 12, 12, 6, 6, 16><<<32 * 36, 512, 0, stream>>>(
      a1, pose1, W1, bu1, ba1, nullptr, nullptr, a2, pose2);
  k_routing<3, 1, 1, 6, 6, 6, 6, 16><<<32 * 36, 512, 0, stream>>>(
      a2, pose2, W2, bu2, ba2, bnc1_g, bnc1_b, a3, pose3);
  k_routing<4, 1, 1, 6, 6, 5, 5, 10><<<32 * 25, 512, 0, stream>>>(
      a3, pose3, Wfc, bufc, bafc, bnc2_g, bnc2_b, a4, nullptr);
  k_mean<<<5, 64, 0, stream>>>(a4, (float*)d_out);
}